// Round 4
// baseline (517.243 us; speedup 1.0000x reference)
//
#include <hip/hip_runtime.h>
#include <stdint.h>

#define N_NODES 50000
#define NNZ     800000
#define SUP     3
#define D_IN    512
#define D_OUT   256
#define TOT_E   (SUP * NNZ)          // 2,400,000
#define NBUCK   391                  // ceil(50000/128) : 128-row buckets
#define CAP     6976                 // per-bucket capacity (mean 6144, +10.6 sigma)
#define CHUNK   6144                 // edges per pass-1 block

typedef __attribute__((ext_vector_type(8))) short bf16x8;
typedef __attribute__((ext_vector_type(4))) float f32x4;

static __device__ __forceinline__ unsigned short f2bf(float f) {
    unsigned int u = __float_as_uint(f);
    unsigned int r = (u + 0x7fffu + ((u >> 16) & 1u)) >> 16;
    return (unsigned short)r;
}
static __device__ __forceinline__ unsigned int pack_bf2(float lo, float hi) {
    unsigned int a = __float_as_uint(lo) + 0x8000u;
    unsigned int b = __float_as_uint(hi) + 0x8000u;
    return (a >> 16) | (b & 0xffff0000u);
}
static __device__ __forceinline__ float bf2f(unsigned short h) {
    return __uint_as_float(((unsigned int)h) << 16);
}

// ---------------- W transpose + bf16 cast: W[s][k][n] -> Wt[s][n][k] ----------------
__global__ void wprep_kernel(const float* __restrict__ W, unsigned short* __restrict__ Wt) {
    int idx = blockIdx.x * 256 + threadIdx.x;
    if (idx >= SUP * D_IN * D_OUT) return;
    int n = idx & (D_OUT - 1);
    int k = (idx >> 8) & (D_IN - 1);
    int s = idx >> 17;
    Wt[((size_t)s * D_OUT + n) * D_IN + k] = f2bf(W[idx]);
}

// ---------------- pass 1: bucket edges by row>>7, coalesced run writes --------------
__global__ __launch_bounds__(256) void bucket_kernel(const int* __restrict__ rows,
                                                     const int* __restrict__ cols,
                                                     const float* __restrict__ vals,
                                                     const float* __restrict__ cw,
                                                     int* __restrict__ bucket_cursor,
                                                     int2* __restrict__ buck) {
    __shared__ int hist[NBUCK];
    __shared__ int sc[256];
    __shared__ int sstart[NBUCK];
    __shared__ int lcur[NBUCK];
    __shared__ int gbase[NBUCK];
    __shared__ unsigned short bucket_of[CHUNK];
    __shared__ int2 stage[CHUNK];    // 48 KB

    const int tid = threadIdx.x;
    const int base_n = blockIdx.x * CHUNK;
    const int count = min(CHUNK, TOT_E - base_n);
    float cw0 = cw[0], cw1 = cw[1], cw2 = cw[2];

    for (int i = tid; i < NBUCK; i += 256) hist[i] = 0;
    __syncthreads();
    for (int i = tid; i < count; i += 256) {
        atomicAdd(&hist[rows[base_n + i] >> 7], 1);
    }
    __syncthreads();
    // scan over NBUCK (<=512) with 2 buckets/thread
    int b0 = 2 * tid, b1 = b0 + 1;
    int h0 = (b0 < NBUCK) ? hist[b0] : 0;
    int h1 = (b1 < NBUCK) ? hist[b1] : 0;
    sc[tid] = h0 + h1;
    __syncthreads();
    for (int off = 1; off < 256; off <<= 1) {
        int t = (tid >= off) ? sc[tid - off] : 0;
        __syncthreads();
        sc[tid] += t;
        __syncthreads();
    }
    int excl = sc[tid] - (h0 + h1);
    if (b0 < NBUCK) { sstart[b0] = excl;      lcur[b0] = excl; }
    if (b1 < NBUCK) { sstart[b1] = excl + h0; lcur[b1] = excl + h0; }
    for (int i = tid; i < NBUCK; i += 256)
        gbase[i] = atomicAdd(&bucket_cursor[i], hist[i]);
    __syncthreads();
    // place into LDS staging, grouped by bucket
    for (int i = tid; i < count; i += 256) {
        int n = base_n + i;
        int r = rows[n];
        int c = cols[n];
        float v = vals[n];
        int s = n / NNZ;
        float w = v * (s == 0 ? cw0 : (s == 1 ? cw1 : cw2));
        int b = r >> 7;
        int p = atomicAdd(&lcur[b], 1);
        stage[p] = make_int2(((r & 127) << 18) | (s * N_NODES + c), __float_as_int(w));
        bucket_of[p] = (unsigned short)b;
    }
    __syncthreads();
    // write out: contiguous runs per bucket
    for (int i = tid; i < count; i += 256) {
        int b = bucket_of[i];
        int local_off = i - sstart[b];
        buck[(size_t)b * CAP + gbase[b] + local_off] = stage[i];
    }
}

// ---------------- pass 2: sort each 128-row bucket via LDS, emit CSR + base/cnt -----
__global__ __launch_bounds__(256) void sort_kernel(const int2* __restrict__ buck,
                                                   const int* __restrict__ bucket_cursor,
                                                   int2* __restrict__ cv,
                                                   int* __restrict__ base,
                                                   int* __restrict__ cnt) {
    __shared__ int hist[128];
    __shared__ int sc[128];
    __shared__ int sstart[128];
    __shared__ int cur[128];
    __shared__ int2 stage[CAP];      // 54.5 KB

    const int b = blockIdx.x;
    const int tid = threadIdx.x;
    const int sz = bucket_cursor[b];
    const int2* src = buck + (size_t)b * CAP;

    if (tid < 128) hist[tid] = 0;
    __syncthreads();
    for (int i = tid; i < sz; i += 256) {
        atomicAdd(&hist[((unsigned)src[i].x) >> 18], 1);
    }
    __syncthreads();
    if (tid < 128) sc[tid] = hist[tid];
    __syncthreads();
    for (int off = 1; off < 128; off <<= 1) {
        int t = (tid >= off && tid < 128) ? sc[tid - off] : 0;
        __syncthreads();
        if (tid < 128) sc[tid] += t;
        __syncthreads();
    }
    if (tid < 128) {
        int st = sc[tid] - hist[tid];
        sstart[tid] = st;
        cur[tid] = st;
    }
    __syncthreads();
    for (int i = tid; i < sz; i += 256) {
        int2 e = src[i];
        int rl = ((unsigned)e.x) >> 18;
        int p = atomicAdd(&cur[rl], 1);
        stage[p] = make_int2(e.x & 0x3FFFF, e.y);
    }
    __syncthreads();
    size_t gb = (size_t)b * CAP;
    for (int i = tid; i < sz; i += 256) cv[gb + i] = stage[i];
    int r = b * 128 + tid;
    if (tid < 128 && r < N_NODES) {
        base[r] = (int)gb + sstart[tid];
        cnt[r]  = hist[tid];
    }
}

// ---------------- bf16 MFMA GEMM: pre[s] = x @ W[s], stored bf16 -------------------
// grid (6, 391): x = (n-tile, support) so A-tile sharers are dispatch-adjacent
__global__ __launch_bounds__(256) void gemm_kernel(const float* __restrict__ x,
                                                   const unsigned short* __restrict__ Wt,
                                                   unsigned short* __restrict__ pre) {
    __shared__ unsigned short lds_a[128 * 40];
    __shared__ unsigned short lds_b[128 * 40];
    const int m0 = blockIdx.y * 128;
    const int n0 = (blockIdx.x & 1) * 128;
    const int s  = blockIdx.x >> 1;
    const unsigned short* wt = Wt + (size_t)s * D_OUT * D_IN;
    const int tid  = threadIdx.x;
    const int wave = tid >> 6;
    const int lane = tid & 63;
    const int quad = lane >> 4;
    const int lo   = lane & 15;
    const int wm = (wave & 1) * 64;
    const int wn = (wave >> 1) * 64;

    f32x4 acc[4][4] = {};

    const int ar = tid >> 1;
    const int ac = (tid & 1) * 16;
    const int gm = m0 + ar;
    const float* xrow = x + (size_t)gm * D_IN;
    const unsigned short* wrow = wt + (size_t)(n0 + ar) * D_IN;

    for (int kb = 0; kb < D_IN; kb += 32) {
        unsigned int aw[8];
        if (gm < N_NODES) {
            float4 f0 = *(const float4*)(xrow + kb + ac);
            float4 f1 = *(const float4*)(xrow + kb + ac + 4);
            float4 f2 = *(const float4*)(xrow + kb + ac + 8);
            float4 f3 = *(const float4*)(xrow + kb + ac + 12);
            aw[0] = pack_bf2(f0.x, f0.y); aw[1] = pack_bf2(f0.z, f0.w);
            aw[2] = pack_bf2(f1.x, f1.y); aw[3] = pack_bf2(f1.z, f1.w);
            aw[4] = pack_bf2(f2.x, f2.y); aw[5] = pack_bf2(f2.z, f2.w);
            aw[6] = pack_bf2(f3.x, f3.y); aw[7] = pack_bf2(f3.z, f3.w);
        } else {
            #pragma unroll
            for (int q = 0; q < 8; ++q) aw[q] = 0;
        }
        uint4 b0 = *(const uint4*)(wrow + kb + ac);
        uint4 b1 = *(const uint4*)(wrow + kb + ac + 8);

        __syncthreads();
        *(uint4*)&lds_a[ar * 40 + ac]     = make_uint4(aw[0], aw[1], aw[2], aw[3]);
        *(uint4*)&lds_a[ar * 40 + ac + 8] = make_uint4(aw[4], aw[5], aw[6], aw[7]);
        *(uint4*)&lds_b[ar * 40 + ac]     = b0;
        *(uint4*)&lds_b[ar * 40 + ac + 8] = b1;
        __syncthreads();

        bf16x8 af[4], bfr[4];
        #pragma unroll
        for (int i = 0; i < 4; ++i)
            af[i] = *(const bf16x8*)&lds_a[(wm + 16 * i + lo) * 40 + quad * 8];
        #pragma unroll
        for (int j = 0; j < 4; ++j)
            bfr[j] = *(const bf16x8*)&lds_b[(wn + 16 * j + lo) * 40 + quad * 8];
        #pragma unroll
        for (int i = 0; i < 4; ++i)
            #pragma unroll
            for (int j = 0; j < 4; ++j)
                acc[i][j] = __builtin_amdgcn_mfma_f32_16x16x32_bf16(af[i], bfr[j], acc[i][j], 0, 0, 0);
    }

    #pragma unroll
    for (int i = 0; i < 4; ++i) {
        #pragma unroll
        for (int j = 0; j < 4; ++j) {
            int gn = n0 + wn + 16 * j + lo;
            #pragma unroll
            for (int r = 0; r < 4; ++r) {
                int gm2 = m0 + wm + 16 * i + quad * 4 + r;
                if (gm2 < N_NODES)
                    pre[((size_t)s * N_NODES + gm2) * D_OUT + gn] = f2bf(acc[i][j][r]);
            }
        }
    }
}

// ---------------- fused SpMM (combined CSR) + ReLU, unroll x8 ----------------------
__global__ __launch_bounds__(256) void spmm_kernel(const unsigned short* __restrict__ pre,
                                                   const int* __restrict__ base,
                                                   const int* __restrict__ cnt,
                                                   const int2* __restrict__ cv,
                                                   float* __restrict__ out) {
    int row  = blockIdx.x * 4 + (threadIdx.x >> 6);
    int lane = threadIdx.x & 63;
    int start = base[row];
    int end   = start + cnt[row];
    float a0 = 0.f, a1 = 0.f, a2 = 0.f, a3 = 0.f;
    int j = start;
    for (; j + 8 <= end; j += 8) {
        int2 e[8];
        #pragma unroll
        for (int q = 0; q < 8; ++q) e[q] = cv[j + q];
        ushort4 p[8];
        #pragma unroll
        for (int q = 0; q < 8; ++q)
            p[q] = *(const ushort4*)(pre + (size_t)e[q].x * D_OUT + lane * 4);
        #pragma unroll
        for (int q = 0; q < 8; ++q) {
            float w = __int_as_float(e[q].y);
            a0 += w * bf2f(p[q].x);
            a1 += w * bf2f(p[q].y);
            a2 += w * bf2f(p[q].z);
            a3 += w * bf2f(p[q].w);
        }
    }
    for (; j + 4 <= end; j += 4) {
        int2 e[4];
        #pragma unroll
        for (int q = 0; q < 4; ++q) e[q] = cv[j + q];
        ushort4 p[4];
        #pragma unroll
        for (int q = 0; q < 4; ++q)
            p[q] = *(const ushort4*)(pre + (size_t)e[q].x * D_OUT + lane * 4);
        #pragma unroll
        for (int q = 0; q < 4; ++q) {
            float w = __int_as_float(e[q].y);
            a0 += w * bf2f(p[q].x);
            a1 += w * bf2f(p[q].y);
            a2 += w * bf2f(p[q].z);
            a3 += w * bf2f(p[q].w);
        }
    }
    for (; j < end; ++j) {
        int2 e = cv[j];
        float w = __int_as_float(e.y);
        ushort4 p = *(const ushort4*)(pre + (size_t)e.x * D_OUT + lane * 4);
        a0 += w * bf2f(p.x);
        a1 += w * bf2f(p.y);
        a2 += w * bf2f(p.z);
        a3 += w * bf2f(p.w);
    }
    float4 o = make_float4(fmaxf(a0, 0.f), fmaxf(a1, 0.f), fmaxf(a2, 0.f), fmaxf(a3, 0.f));
    *(float4*)(out + (size_t)row * D_OUT + lane * 4) = o;
}

extern "C" void kernel_launch(void* const* d_in, const int* in_sizes, int n_in,
                              void* d_out, int out_size, void* d_ws, size_t ws_size,
                              hipStream_t stream) {
    const float* x    = (const float*)d_in[0];
    const float* W    = (const float*)d_in[1];
    const int*   rows = (const int*)d_in[2];
    const int*   cols = (const int*)d_in[3];
    const float* vals = (const float*)d_in[4];
    const float* cw   = (const float*)d_in[5];
    float* out = (float*)d_out;

    char* ws = (char*)d_ws;
    size_t off = 0;
    auto alloc = [&](size_t bytes) -> void* {
        void* p = ws + off;
        off += (bytes + 255) & ~(size_t)255;
        return p;
    };
    unsigned short* pre  = (unsigned short*)alloc((size_t)SUP * N_NODES * D_OUT * 2); // 76.8 MB
    unsigned short* Wt   = (unsigned short*)alloc((size_t)SUP * D_OUT * D_IN * 2);    // 0.8 MB
    int* base            = (int*)alloc((size_t)N_NODES * 4);
    int* cnt             = (int*)alloc((size_t)N_NODES * 4);
    int* bucket_cursor   = (int*)alloc((size_t)NBUCK * 4);
    int2* cv             = (int2*)alloc((size_t)NBUCK * CAP * 8);                     // 21.8 MB
    // buck aliases the pre region (dead before gemm writes pre; stream-ordered)
    int2* buck           = (int2*)pre;

    hipMemsetAsync(bucket_cursor, 0, (size_t)NBUCK * 4, stream);

    bucket_kernel<<<(TOT_E + CHUNK - 1) / CHUNK, 256, 0, stream>>>(rows, cols, vals, cw,
                                                                   bucket_cursor, buck);
    sort_kernel<<<NBUCK, 256, 0, stream>>>(buck, bucket_cursor, cv, base, cnt);
    wprep_kernel<<<(SUP * D_IN * D_OUT + 255) / 256, 256, 0, stream>>>(W, Wt);
    gemm_kernel<<<dim3(6, 391), 256, 0, stream>>>(x, Wt, pre);
    spmm_kernel<<<N_NODES / 4, 256, 0, stream>>>(pre, base, cnt, cv, out);
}

// Round 5
// 493.038 us; speedup vs baseline: 1.0491x; 1.0491x over previous
//
#include <hip/hip_runtime.h>
#include <stdint.h>

#define N_NODES 50000
#define N_PAD   50048                // padded to 128-row multiple for gemm tiles
#define NNZ     800000
#define SUP     3
#define D_IN    512
#define D_OUT   256
#define TOT_E   (SUP * NNZ)          // 2,400,000
#define NBUCK   391                  // ceil(50000/128) : 128-row buckets
#define CAP     6976                 // per-bucket capacity (mean 6144, +10.6 sigma)
#define CHUNK   6144                 // edges per pass-1 block

typedef __attribute__((ext_vector_type(8))) short bf16x8;
typedef __attribute__((ext_vector_type(4))) float f32x4;
typedef __attribute__((address_space(3))) unsigned int lds_u32_t;
typedef const __attribute__((address_space(1))) unsigned int glb_u32_t;

static __device__ __forceinline__ unsigned short f2bf(float f) {
    unsigned int u = __float_as_uint(f);
    unsigned int r = (u + 0x7fffu + ((u >> 16) & 1u)) >> 16;
    return (unsigned short)r;
}
static __device__ __forceinline__ unsigned int pack_bf2(float lo, float hi) {
    unsigned int a = __float_as_uint(lo) + 0x8000u;
    unsigned int b = __float_as_uint(hi) + 0x8000u;
    return (a >> 16) | (b & 0xffff0000u);
}
static __device__ __forceinline__ float bf2f(unsigned short h) {
    return __uint_as_float(((unsigned int)h) << 16);
}

// ---------------- x fp32 -> bf16 (one-time), 8 elems/thread ------------------------
__global__ void xprep_kernel(const float* __restrict__ x, unsigned int* __restrict__ xb) {
    int idx = blockIdx.x * 256 + threadIdx.x;      // over 50000*512/8 = 3,200,000
    if (idx >= N_NODES * D_IN / 8) return;
    const float4* src = (const float4*)(x) + idx * 2;
    float4 f0 = src[0];
    float4 f1 = src[1];
    uint4 o;
    o.x = pack_bf2(f0.x, f0.y);
    o.y = pack_bf2(f0.z, f0.w);
    o.z = pack_bf2(f1.x, f1.y);
    o.w = pack_bf2(f1.z, f1.w);
    *((uint4*)xb + idx) = o;
}

// ---------------- W transpose + bf16 cast: W[s][k][n] -> Wt[s][n][k] ----------------
__global__ void wprep_kernel(const float* __restrict__ W, unsigned short* __restrict__ Wt) {
    int idx = blockIdx.x * 256 + threadIdx.x;
    if (idx >= SUP * D_IN * D_OUT) return;
    int n = idx & (D_OUT - 1);
    int k = (idx >> 8) & (D_IN - 1);
    int s = idx >> 17;
    Wt[((size_t)s * D_OUT + n) * D_IN + k] = f2bf(W[idx]);
}

// ---------------- pass 1: bucket edges by row>>7, coalesced run writes --------------
__global__ __launch_bounds__(256) void bucket_kernel(const int* __restrict__ rows,
                                                     const int* __restrict__ cols,
                                                     const float* __restrict__ vals,
                                                     const float* __restrict__ cw,
                                                     int* __restrict__ bucket_cursor,
                                                     int2* __restrict__ buck) {
    __shared__ int hist[NBUCK];
    __shared__ int sc[256];
    __shared__ int sstart[NBUCK];
    __shared__ int lcur[NBUCK];
    __shared__ int gbase[NBUCK];
    __shared__ unsigned short bucket_of[CHUNK];
    __shared__ int2 stage[CHUNK];

    const int tid = threadIdx.x;
    const int base_n = blockIdx.x * CHUNK;
    const int count = min(CHUNK, TOT_E - base_n);
    float cw0 = cw[0], cw1 = cw[1], cw2 = cw[2];

    for (int i = tid; i < NBUCK; i += 256) hist[i] = 0;
    __syncthreads();
    for (int i = tid; i < count; i += 256) {
        atomicAdd(&hist[rows[base_n + i] >> 7], 1);
    }
    __syncthreads();
    int b0 = 2 * tid, b1 = b0 + 1;
    int h0 = (b0 < NBUCK) ? hist[b0] : 0;
    int h1 = (b1 < NBUCK) ? hist[b1] : 0;
    sc[tid] = h0 + h1;
    __syncthreads();
    for (int off = 1; off < 256; off <<= 1) {
        int t = (tid >= off) ? sc[tid - off] : 0;
        __syncthreads();
        sc[tid] += t;
        __syncthreads();
    }
    int excl = sc[tid] - (h0 + h1);
    if (b0 < NBUCK) { sstart[b0] = excl;      lcur[b0] = excl; }
    if (b1 < NBUCK) { sstart[b1] = excl + h0; lcur[b1] = excl + h0; }
    for (int i = tid; i < NBUCK; i += 256)
        gbase[i] = atomicAdd(&bucket_cursor[i], hist[i]);
    __syncthreads();
    for (int i = tid; i < count; i += 256) {
        int n = base_n + i;
        int r = rows[n];
        int c = cols[n];
        float v = vals[n];
        int s = n / NNZ;
        float w = v * (s == 0 ? cw0 : (s == 1 ? cw1 : cw2));
        int b = r >> 7;
        int p = atomicAdd(&lcur[b], 1);
        stage[p] = make_int2(((r & 127) << 18) | (s * N_NODES + c), __float_as_int(w));
        bucket_of[p] = (unsigned short)b;
    }
    __syncthreads();
    for (int i = tid; i < count; i += 256) {
        int b = bucket_of[i];
        int local_off = i - sstart[b];
        buck[(size_t)b * CAP + gbase[b] + local_off] = stage[i];
    }
}

// ---------------- pass 2: sort each 128-row bucket via LDS, emit CSR + base/cnt -----
__global__ __launch_bounds__(256) void sort_kernel(const int2* __restrict__ buck,
                                                   const int* __restrict__ bucket_cursor,
                                                   int2* __restrict__ cv,
                                                   int* __restrict__ base,
                                                   int* __restrict__ cnt) {
    __shared__ int hist[128];
    __shared__ int sc[128];
    __shared__ int sstart[128];
    __shared__ int cur[128];
    __shared__ int2 stage[CAP];

    const int b = blockIdx.x;
    const int tid = threadIdx.x;
    const int sz = bucket_cursor[b];
    const int2* src = buck + (size_t)b * CAP;

    if (tid < 128) hist[tid] = 0;
    __syncthreads();
    for (int i = tid; i < sz; i += 256) {
        atomicAdd(&hist[((unsigned)src[i].x) >> 18], 1);
    }
    __syncthreads();
    if (tid < 128) sc[tid] = hist[tid];
    __syncthreads();
    for (int off = 1; off < 128; off <<= 1) {
        int t = (tid >= off && tid < 128) ? sc[tid - off] : 0;
        __syncthreads();
        if (tid < 128) sc[tid] += t;
        __syncthreads();
    }
    if (tid < 128) {
        int st = sc[tid] - hist[tid];
        sstart[tid] = st;
        cur[tid] = st;
    }
    __syncthreads();
    for (int i = tid; i < sz; i += 256) {
        int2 e = src[i];
        int rl = ((unsigned)e.x) >> 18;
        int p = atomicAdd(&cur[rl], 1);
        stage[p] = make_int2(e.x & 0x3FFFF, e.y);
    }
    __syncthreads();
    size_t gb = (size_t)b * CAP;
    for (int i = tid; i < sz; i += 256) cv[gb + i] = stage[i];
    int r = b * 128 + tid;
    if (tid < 128 && r < N_NODES) {
        base[r] = (int)gb + sstart[tid];
        cnt[r]  = hist[tid];
    }
}

// ---------------- m97-style bf16 MFMA GEMM: pre[s] = xb @ Wt[s]^T ------------------
// BM=BN=128, BK=64. A/B staged via global_load_lds width-16 (zero staging VALU).
// grid (6, 391): x = (n-tile, support), y = m-tile.
__global__ __launch_bounds__(256) void gemm_kernel(const unsigned short* __restrict__ xb,
                                                   const unsigned short* __restrict__ Wt,
                                                   unsigned short* __restrict__ pre) {
    __shared__ unsigned short lds_a[128 * 64];   // 16 KB, [row][64k]
    __shared__ unsigned short lds_b[128 * 64];   // 16 KB, [n][64k]
    const int m0 = blockIdx.y * 128;
    const int n0 = (blockIdx.x & 1) * 128;
    const int s  = blockIdx.x >> 1;
    const unsigned short* wt = Wt + (size_t)s * D_OUT * D_IN;
    const int tid  = threadIdx.x;
    const int wave = tid >> 6;
    const int lane = tid & 63;
    const int quad = lane >> 4;
    const int lo   = lane & 15;
    const int wm = (wave & 1) * 64;
    const int wn = (wave >> 1) * 64;

    f32x4 acc[4][4] = {};

    for (int kb = 0; kb < D_IN; kb += 64) {
        __syncthreads();   // previous iteration's LDS reads done
        // stage A tile (128 rows x 64 k, 1024 x 16B chunks) and B tile
        #pragma unroll
        for (int c = 0; c < 4; ++c) {
            int idx = c * 256 + tid;            // chunk id 0..1023
            int row = idx >> 3;                 // 8 chunks of 16B per 128B row
            int kp  = idx & 7;
            const unsigned short* ga = xb + (size_t)(m0 + row) * D_IN + kb + kp * 8;
            __builtin_amdgcn_global_load_lds((glb_u32_t*)ga,
                                             (lds_u32_t*)&lds_a[idx * 8], 16, 0, 0);
            const unsigned short* gb = wt + (size_t)(n0 + row) * D_IN + kb + kp * 8;
            __builtin_amdgcn_global_load_lds((glb_u32_t*)gb,
                                             (lds_u32_t*)&lds_b[idx * 8], 16, 0, 0);
        }
        __syncthreads();

        #pragma unroll
        for (int t = 0; t < 2; ++t) {
            bf16x8 af[4], bfr[4];
            #pragma unroll
            for (int i = 0; i < 4; ++i)
                af[i] = *(const bf16x8*)&lds_a[(wm + 16 * i + lo) * 64 + t * 32 + quad * 8];
            #pragma unroll
            for (int j = 0; j < 4; ++j)
                bfr[j] = *(const bf16x8*)&lds_b[(wn + 16 * j + lo) * 64 + t * 32 + quad * 8];
            #pragma unroll
            for (int i = 0; i < 4; ++i)
                #pragma unroll
                for (int j = 0; j < 4; ++j)
                    acc[i][j] = __builtin_amdgcn_mfma_f32_16x16x32_bf16(af[i], bfr[j], acc[i][j], 0, 0, 0);
        }
    }

    // epilogue: C layout col=lane&15, row=quad*4+reg
    #pragma unroll
    for (int i = 0; i < 4; ++i) {
        #pragma unroll
        for (int j = 0; j < 4; ++j) {
            int gn = n0 + wn + 16 * j + lo;
            #pragma unroll
            for (int r = 0; r < 4; ++r) {
                int gm2 = m0 + wm + 16 * i + quad * 4 + r;
                if (gm2 < N_NODES)
                    pre[((size_t)s * N_NODES + gm2) * D_OUT + gn] = f2bf(acc[i][j][r]);
            }
        }
    }
}

// ---------------- fused SpMM (combined CSR) + ReLU, unroll x8 ----------------------
__global__ __launch_bounds__(256) void spmm_kernel(const unsigned short* __restrict__ pre,
                                                   const int* __restrict__ base,
                                                   const int* __restrict__ cnt,
                                                   const int2* __restrict__ cv,
                                                   float* __restrict__ out) {
    int row  = blockIdx.x * 4 + (threadIdx.x >> 6);
    int lane = threadIdx.x & 63;
    int start = base[row];
    int end   = start + cnt[row];
    float a0 = 0.f, a1 = 0.f, a2 = 0.f, a3 = 0.f;
    int j = start;
    for (; j + 8 <= end; j += 8) {
        int2 e[8];
        #pragma unroll
        for (int q = 0; q < 8; ++q) e[q] = cv[j + q];
        ushort4 p[8];
        #pragma unroll
        for (int q = 0; q < 8; ++q)
            p[q] = *(const ushort4*)(pre + (size_t)e[q].x * D_OUT + lane * 4);
        #pragma unroll
        for (int q = 0; q < 8; ++q) {
            float w = __int_as_float(e[q].y);
            a0 += w * bf2f(p[q].x);
            a1 += w * bf2f(p[q].y);
            a2 += w * bf2f(p[q].z);
            a3 += w * bf2f(p[q].w);
        }
    }
    for (; j + 4 <= end; j += 4) {
        int2 e[4];
        #pragma unroll
        for (int q = 0; q < 4; ++q) e[q] = cv[j + q];
        ushort4 p[4];
        #pragma unroll
        for (int q = 0; q < 4; ++q)
            p[q] = *(const ushort4*)(pre + (size_t)e[q].x * D_OUT + lane * 4);
        #pragma unroll
        for (int q = 0; q < 4; ++q) {
            float w = __int_as_float(e[q].y);
            a0 += w * bf2f(p[q].x);
            a1 += w * bf2f(p[q].y);
            a2 += w * bf2f(p[q].z);
            a3 += w * bf2f(p[q].w);
        }
    }
    for (; j < end; ++j) {
        int2 e = cv[j];
        float w = __int_as_float(e.y);
        ushort4 p = *(const ushort4*)(pre + (size_t)e.x * D_OUT + lane * 4);
        a0 += w * bf2f(p.x);
        a1 += w * bf2f(p.y);
        a2 += w * bf2f(p.z);
        a3 += w * bf2f(p.w);
    }
    float4 o = make_float4(fmaxf(a0, 0.f), fmaxf(a1, 0.f), fmaxf(a2, 0.f), fmaxf(a3, 0.f));
    *(float4*)(out + (size_t)row * D_OUT + lane * 4) = o;
}

extern "C" void kernel_launch(void* const* d_in, const int* in_sizes, int n_in,
                              void* d_out, int out_size, void* d_ws, size_t ws_size,
                              hipStream_t stream) {
    const float* x    = (const float*)d_in[0];
    const float* W    = (const float*)d_in[1];
    const int*   rows = (const int*)d_in[2];
    const int*   cols = (const int*)d_in[3];
    const float* vals = (const float*)d_in[4];
    const float* cw   = (const float*)d_in[5];
    float* out = (float*)d_out;

    char* ws = (char*)d_ws;
    size_t off = 0;
    auto alloc = [&](size_t bytes) -> void* {
        void* p = ws + off;
        off += (bytes + 255) & ~(size_t)255;
        return p;
    };
    unsigned short* pre  = (unsigned short*)alloc((size_t)SUP * N_NODES * D_OUT * 2); // 76.8 MB
    unsigned short* xb   = (unsigned short*)alloc((size_t)N_PAD * D_IN * 2);          // 51.2 MB
    unsigned short* Wt   = (unsigned short*)alloc((size_t)SUP * D_OUT * D_IN * 2);    // 0.8 MB
    int* base            = (int*)alloc((size_t)N_NODES * 4);
    int* cnt             = (int*)alloc((size_t)N_NODES * 4);
    int* bucket_cursor   = (int*)alloc((size_t)NBUCK * 4);
    int2* cv             = (int2*)alloc((size_t)NBUCK * CAP * 8);                     // 21.8 MB
    // buck aliases the pre region (dead before gemm writes pre; stream-ordered)
    int2* buck           = (int2*)pre;

    hipMemsetAsync(bucket_cursor, 0, (size_t)NBUCK * 4, stream);

    bucket_kernel<<<(TOT_E + CHUNK - 1) / CHUNK, 256, 0, stream>>>(rows, cols, vals, cw,
                                                                   bucket_cursor, buck);
    sort_kernel<<<NBUCK, 256, 0, stream>>>(buck, bucket_cursor, cv, base, cnt);
    xprep_kernel<<<(N_NODES * D_IN / 8 + 255) / 256, 256, 0, stream>>>(x, (unsigned int*)xb);
    wprep_kernel<<<(SUP * D_IN * D_OUT + 255) / 256, 256, 0, stream>>>(W, Wt);
    gemm_kernel<<<dim3(6, 391), 256, 0, stream>>>(xb, Wt, pre);
    spmm_kernel<<<N_NODES / 4, 256, 0, stream>>>(pre, base, cnt, cv, out);
}

// Round 6
// 474.499 us; speedup vs baseline: 1.0901x; 1.0391x over previous
//
#include <hip/hip_runtime.h>
#include <stdint.h>

#define N_NODES 50000
#define N_PAD   50048                // padded to 128-row multiple for gemm tiles
#define NNZ     800000
#define SUP     3
#define D_IN    512
#define D_OUT   256
#define TOT_E   (SUP * NNZ)          // 2,400,000
#define NBUCK   391                  // ceil(50000/128) : 128-row buckets
#define CAP     6976                 // per-bucket capacity (mean 6144, +10.6 sigma)
#define CHUNK   6144                 // edges per bucket block
#define NB_WPREP 1536                // 393216 / 256
#define NB_XPREP 12500               // 3,200,000 / 256
#define NB_GEMM  2346                // 391 m-tiles * 6 (n-tile x support)

typedef __attribute__((ext_vector_type(8))) short bf16x8;
typedef __attribute__((ext_vector_type(4))) float f32x4;
typedef __attribute__((address_space(3))) unsigned int lds_u32_t;
typedef const __attribute__((address_space(1))) unsigned int glb_u32_t;

static __device__ __forceinline__ unsigned short f2bf(float f) {
    unsigned int u = __float_as_uint(f);
    unsigned int r = (u + 0x7fffu + ((u >> 16) & 1u)) >> 16;
    return (unsigned short)r;
}
static __device__ __forceinline__ unsigned int pack_bf2(float lo, float hi) {
    unsigned int a = __float_as_uint(lo) + 0x8000u;
    unsigned int b = __float_as_uint(hi) + 0x8000u;
    return (a >> 16) | (b & 0xffff0000u);
}
static __device__ __forceinline__ float bf2f(unsigned short h) {
    return __uint_as_float(((unsigned int)h) << 16);
}

// ============ fused prep: [0,391) bucket | [391,1927) wprep | [1927,14427) xprep ====
__global__ __launch_bounds__(256) void prep_kernel(const int* __restrict__ rows,
                                                   const int* __restrict__ cols,
                                                   const float* __restrict__ vals,
                                                   const float* __restrict__ cw,
                                                   int* __restrict__ bucket_cursor,
                                                   int2* __restrict__ buck,
                                                   const float* __restrict__ x,
                                                   unsigned int* __restrict__ xb,
                                                   const float* __restrict__ W,
                                                   unsigned short* __restrict__ Wt) {
    __shared__ double smem8[8590];           // 68720 B union
    char* smem = (char*)smem8;
    const int blk = blockIdx.x;
    const int tid = threadIdx.x;

    if (blk < NBUCK) {
        // ---- bucket: edges by row>>7, coalesced run writes ----
        int2* stage = (int2*)smem;                               // 49152 B
        unsigned short* bucket_of = (unsigned short*)(smem + 49152); // 12288 B
        int* hist   = (int*)(smem + 61440);                      // [391]
        int* sc     = hist + NBUCK;                              // [256]
        int* sstart = sc + 256;                                  // [391]
        int* lcur   = sstart + NBUCK;                            // [391]
        int* gbase  = lcur + NBUCK;                              // [391]

        const int base_n = blk * CHUNK;
        const int count = min(CHUNK, TOT_E - base_n);
        float cw0 = cw[0], cw1 = cw[1], cw2 = cw[2];

        for (int i = tid; i < NBUCK; i += 256) hist[i] = 0;
        __syncthreads();
        for (int i = tid; i < count; i += 256)
            atomicAdd(&hist[rows[base_n + i] >> 7], 1);
        __syncthreads();
        int b0 = 2 * tid, b1 = b0 + 1;
        int h0 = (b0 < NBUCK) ? hist[b0] : 0;
        int h1 = (b1 < NBUCK) ? hist[b1] : 0;
        sc[tid] = h0 + h1;
        __syncthreads();
        for (int off = 1; off < 256; off <<= 1) {
            int t = (tid >= off) ? sc[tid - off] : 0;
            __syncthreads();
            sc[tid] += t;
            __syncthreads();
        }
        int excl = sc[tid] - (h0 + h1);
        if (b0 < NBUCK) { sstart[b0] = excl;      lcur[b0] = excl; }
        if (b1 < NBUCK) { sstart[b1] = excl + h0; lcur[b1] = excl + h0; }
        for (int i = tid; i < NBUCK; i += 256)
            gbase[i] = atomicAdd(&bucket_cursor[i], hist[i]);
        __syncthreads();
        for (int i = tid; i < count; i += 256) {
            int n = base_n + i;
            int r = rows[n];
            int c = cols[n];
            float v = vals[n];
            int s = n / NNZ;
            float w = v * (s == 0 ? cw0 : (s == 1 ? cw1 : cw2));
            int b = r >> 7;
            int p = atomicAdd(&lcur[b], 1);
            stage[p] = make_int2(((r & 127) << 18) | (s * N_NODES + c), __float_as_int(w));
            bucket_of[p] = (unsigned short)b;
        }
        __syncthreads();
        for (int i = tid; i < count; i += 256) {
            int b = bucket_of[i];
            int local_off = i - sstart[b];
            buck[(size_t)b * CAP + gbase[b] + local_off] = stage[i];
        }
    } else if (blk < NBUCK + NB_WPREP) {
        // ---- wprep: W[s][k][n] -> Wt[s][n][k], bf16 ----
        int idx = (blk - NBUCK) * 256 + tid;    // < 393216 exactly
        int n = idx & (D_OUT - 1);
        int k = (idx >> 8) & (D_IN - 1);
        int s = idx >> 17;
        Wt[((size_t)s * D_OUT + n) * D_IN + k] = f2bf(W[idx]);
    } else {
        // ---- xprep: x fp32 -> bf16, 8 elems/thread ----
        int idx = (blk - NBUCK - NB_WPREP) * 256 + tid;   // < 3,200,000 exactly
        const float4* src = (const float4*)(x) + idx * 2;
        float4 f0 = src[0];
        float4 f1 = src[1];
        uint4 o;
        o.x = pack_bf2(f0.x, f0.y);
        o.y = pack_bf2(f0.z, f0.w);
        o.z = pack_bf2(f1.x, f1.y);
        o.w = pack_bf2(f1.z, f1.w);
        *((uint4*)xb + idx) = o;
    }
}

// ============ fused: [0,391) sort | [391,2737) gemm =================================
__global__ __launch_bounds__(256) void sortgemm_kernel(const int2* __restrict__ buck,
                                                       const int* __restrict__ bucket_cursor,
                                                       int2* __restrict__ cv,
                                                       int* __restrict__ base,
                                                       int* __restrict__ cnt,
                                                       const unsigned short* __restrict__ xb,
                                                       const unsigned short* __restrict__ Wt,
                                                       unsigned short* __restrict__ pre) {
    __shared__ double smem8[7232];           // 57856 B union
    char* smem = (char*)smem8;
    const int blk = blockIdx.x;
    const int tid = threadIdx.x;

    if (blk < NBUCK) {
        // ---- sort one 128-row bucket via LDS, emit CSR + base/cnt ----
        int2* stage = (int2*)smem;                   // 55808 B
        int* hist   = (int*)(smem + 55808);          // [128]
        int* sc     = hist + 128;
        int* sstart = sc + 128;
        int* cur    = sstart + 128;

        const int b = blk;
        const int sz = bucket_cursor[b];
        const int2* src = buck + (size_t)b * CAP;

        if (tid < 128) hist[tid] = 0;
        __syncthreads();
        for (int i = tid; i < sz; i += 256)
            atomicAdd(&hist[((unsigned)src[i].x) >> 18], 1);
        __syncthreads();
        if (tid < 128) sc[tid] = hist[tid];
        __syncthreads();
        for (int off = 1; off < 128; off <<= 1) {
            int t = (tid >= off && tid < 128) ? sc[tid - off] : 0;
            __syncthreads();
            if (tid < 128) sc[tid] += t;
            __syncthreads();
        }
        if (tid < 128) {
            int st = sc[tid] - hist[tid];
            sstart[tid] = st;
            cur[tid] = st;
        }
        __syncthreads();
        for (int i = tid; i < sz; i += 256) {
            int2 e = src[i];
            int rl = ((unsigned)e.x) >> 18;
            int p = atomicAdd(&cur[rl], 1);
            stage[p] = make_int2(e.x & 0x3FFFF, e.y);
        }
        __syncthreads();
        size_t gb = (size_t)b * CAP;
        for (int i = tid; i < sz; i += 256) cv[gb + i] = stage[i];
        int r = b * 128 + tid;
        if (tid < 128 && r < N_NODES) {
            base[r] = (int)gb + sstart[tid];
            cnt[r]  = hist[tid];
        }
    } else {
        // ---- m97-style bf16 MFMA GEMM: pre[s] = xb @ Wt[s]^T ----
        unsigned short* lds_a = (unsigned short*)smem;            // 16384 B
        unsigned short* lds_b = (unsigned short*)(smem + 16384);  // 16384 B
        const int my  = blk - NBUCK;           // 0..2345
        const int mt  = my / 6;
        const int rem = my % 6;                // fast index: sharers of m-tile adjacent
        const int m0 = mt * 128;
        const int n0 = (rem & 1) * 128;
        const int s  = rem >> 1;
        const unsigned short* wt = Wt + (size_t)s * D_OUT * D_IN;
        const int wave = tid >> 6;
        const int lane = tid & 63;
        const int quad = lane >> 4;
        const int lo   = lane & 15;
        const int wm = (wave & 1) * 64;
        const int wn = (wave >> 1) * 64;

        f32x4 acc[4][4] = {};

        for (int kb = 0; kb < D_IN; kb += 64) {
            __syncthreads();
            #pragma unroll
            for (int c = 0; c < 4; ++c) {
                int idx = c * 256 + tid;
                int row = idx >> 3;
                int kp  = idx & 7;
                const unsigned short* ga = xb + (size_t)(m0 + row) * D_IN + kb + kp * 8;
                __builtin_amdgcn_global_load_lds((glb_u32_t*)ga,
                                                 (lds_u32_t*)&lds_a[idx * 8], 16, 0, 0);
                const unsigned short* gb = wt + (size_t)(n0 + row) * D_IN + kb + kp * 8;
                __builtin_amdgcn_global_load_lds((glb_u32_t*)gb,
                                                 (lds_u32_t*)&lds_b[idx * 8], 16, 0, 0);
            }
            __syncthreads();

            #pragma unroll
            for (int t = 0; t < 2; ++t) {
                bf16x8 af[4], bfr[4];
                #pragma unroll
                for (int i = 0; i < 4; ++i)
                    af[i] = *(const bf16x8*)&lds_a[(wm + 16 * i + lo) * 64 + t * 32 + quad * 8];
                #pragma unroll
                for (int j = 0; j < 4; ++j)
                    bfr[j] = *(const bf16x8*)&lds_b[(wn + 16 * j + lo) * 64 + t * 32 + quad * 8];
                #pragma unroll
                for (int i = 0; i < 4; ++i)
                    #pragma unroll
                    for (int j = 0; j < 4; ++j)
                        acc[i][j] = __builtin_amdgcn_mfma_f32_16x16x32_bf16(af[i], bfr[j], acc[i][j], 0, 0, 0);
            }
        }

        // epilogue: C layout col=lane&15, row=quad*4+reg
        #pragma unroll
        for (int i = 0; i < 4; ++i) {
            #pragma unroll
            for (int j = 0; j < 4; ++j) {
                int gn = n0 + wn + 16 * j + lo;
                #pragma unroll
                for (int r = 0; r < 4; ++r) {
                    int gm2 = m0 + wm + 16 * i + quad * 4 + r;
                    if (gm2 < N_NODES)
                        pre[((size_t)s * N_NODES + gm2) * D_OUT + gn] = f2bf(acc[i][j][r]);
                }
            }
        }
    }
}

// ---------------- fused SpMM (combined CSR) + ReLU, unroll x8 ----------------------
__global__ __launch_bounds__(256) void spmm_kernel(const unsigned short* __restrict__ pre,
                                                   const int* __restrict__ base,
                                                   const int* __restrict__ cnt,
                                                   const int2* __restrict__ cv,
                                                   float* __restrict__ out) {
    int row  = blockIdx.x * 4 + (threadIdx.x >> 6);
    int lane = threadIdx.x & 63;
    int start = base[row];
    int end   = start + cnt[row];
    float a0 = 0.f, a1 = 0.f, a2 = 0.f, a3 = 0.f;
    int j = start;
    for (; j + 8 <= end; j += 8) {
        int2 e[8];
        #pragma unroll
        for (int q = 0; q < 8; ++q) e[q] = cv[j + q];
        ushort4 p[8];
        #pragma unroll
        for (int q = 0; q < 8; ++q)
            p[q] = *(const ushort4*)(pre + (size_t)e[q].x * D_OUT + lane * 4);
        #pragma unroll
        for (int q = 0; q < 8; ++q) {
            float w = __int_as_float(e[q].y);
            a0 += w * bf2f(p[q].x);
            a1 += w * bf2f(p[q].y);
            a2 += w * bf2f(p[q].z);
            a3 += w * bf2f(p[q].w);
        }
    }
    for (; j + 4 <= end; j += 4) {
        int2 e[4];
        #pragma unroll
        for (int q = 0; q < 4; ++q) e[q] = cv[j + q];
        ushort4 p[4];
        #pragma unroll
        for (int q = 0; q < 4; ++q)
            p[q] = *(const ushort4*)(pre + (size_t)e[q].x * D_OUT + lane * 4);
        #pragma unroll
        for (int q = 0; q < 4; ++q) {
            float w = __int_as_float(e[q].y);
            a0 += w * bf2f(p[q].x);
            a1 += w * bf2f(p[q].y);
            a2 += w * bf2f(p[q].z);
            a3 += w * bf2f(p[q].w);
        }
    }
    for (; j < end; ++j) {
        int2 e = cv[j];
        float w = __int_as_float(e.y);
        ushort4 p = *(const ushort4*)(pre + (size_t)e.x * D_OUT + lane * 4);
        a0 += w * bf2f(p.x);
        a1 += w * bf2f(p.y);
        a2 += w * bf2f(p.z);
        a3 += w * bf2f(p.w);
    }
    float4 o = make_float4(fmaxf(a0, 0.f), fmaxf(a1, 0.f), fmaxf(a2, 0.f), fmaxf(a3, 0.f));
    *(float4*)(out + (size_t)row * D_OUT + lane * 4) = o;
}

extern "C" void kernel_launch(void* const* d_in, const int* in_sizes, int n_in,
                              void* d_out, int out_size, void* d_ws, size_t ws_size,
                              hipStream_t stream) {
    const float* x    = (const float*)d_in[0];
    const float* W    = (const float*)d_in[1];
    const int*   rows = (const int*)d_in[2];
    const int*   cols = (const int*)d_in[3];
    const float* vals = (const float*)d_in[4];
    const float* cw   = (const float*)d_in[5];
    float* out = (float*)d_out;

    char* ws = (char*)d_ws;
    size_t off = 0;
    auto alloc = [&](size_t bytes) -> void* {
        void* p = ws + off;
        off += (bytes + 255) & ~(size_t)255;
        return p;
    };
    unsigned short* pre  = (unsigned short*)alloc((size_t)SUP * N_NODES * D_OUT * 2); // 76.8 MB
    unsigned short* xb   = (unsigned short*)alloc((size_t)N_PAD * D_IN * 2);          // 51.25 MB
    unsigned short* Wt   = (unsigned short*)alloc((size_t)SUP * D_OUT * D_IN * 2);    // 0.8 MB
    int* base            = (int*)alloc((size_t)N_NODES * 4);
    int* cnt             = (int*)alloc((size_t)N_NODES * 4);
    int* bucket_cursor   = (int*)alloc((size_t)NBUCK * 4);
    int2* cv             = (int2*)alloc((size_t)NBUCK * CAP * 8);                     // 21.8 MB
    // buck lives in d_out (51.2 MB >= 21.8 MB): written by prep, read by sortgemm,
    // dead before spmm overwrites out.  (Cannot alias pre anymore: gemm writes pre
    // concurrently with sort reading buck inside the fused kernel.)
    int2* buck           = (int2*)d_out;

    hipMemsetAsync(bucket_cursor, 0, (size_t)NBUCK * 4, stream);

    prep_kernel<<<NBUCK + NB_WPREP + NB_XPREP, 256, 0, stream>>>(
        rows, cols, vals, cw, bucket_cursor, buck, x, (unsigned int*)xb, W, Wt);
    sortgemm_kernel<<<NBUCK + NB_GEMM, 256, 0, stream>>>(
        buck, bucket_cursor, cv, base, cnt, xb, Wt, pre);
    spmm_kernel<<<N_NODES / 4, 256, 0, stream>>>(pre, base, cnt, cv, out);
}